// Round 1
// baseline (236.330 us; speedup 1.0000x reference)
//
#include <hip/hip_runtime.h>
#include <math.h>

// N=20000, K=16, in_dim=128, out_dim=128, H1=H2=16, hidden=256
#define IN_DIM 128
#define HID 256
#define OUT_DIM 128
#define KNBR 16

// Kernel 1: pre = feature @ W_aff + b_aff  (per node, 256 outputs),
// then 2D FFT of the 16x16 map via two 16-point DFT-matrix stages.
// Spectra stored split-plane in workspace: Fre[node*256+e], Fim[node*256+e].
__global__ __launch_bounds__(256) void k_pre_fft(
    const float* __restrict__ feat, const float* __restrict__ W_aff,
    const float* __restrict__ b_aff, float* __restrict__ Fre,
    float* __restrict__ Fim)
{
    const int node = blockIdx.x;
    const int tid  = threadIdx.x;            // 0..255
    __shared__ float sf[IN_DIM];
    __shared__ float X[HID];                 // pre, row-major [16][16]
    __shared__ float Yre[HID], Yim[HID];
    __shared__ float twc[16], tws[16];       // exp(-2*pi*i*m/16)

    if (tid < IN_DIM) sf[tid] = feat[node * IN_DIM + tid];
    if (tid < 16) {
        float a = -(float)M_PI * (float)tid / 8.0f;
        twc[tid] = cosf(a);
        tws[tid] = sinf(a);
    }
    __syncthreads();

    // affine: one output element per thread; W_aff column reads are coalesced
    float acc = b_aff[tid];
#pragma unroll 8
    for (int i = 0; i < IN_DIM; ++i)
        acc = fmaf(sf[i], W_aff[i * HID + tid], acc);
    X[tid] = acc;
    __syncthreads();

    const int r = tid >> 4;   // row 0..15
    const int v = tid & 15;   // col 0..15

    // stage A: FFT along last axis: Y[r][v] = sum_c X[r][c] * tw[(c*v)&15]
    float yre = 0.f, yim = 0.f;
#pragma unroll
    for (int c = 0; c < 16; ++c) {
        int m = (c * v) & 15;
        float x = X[r * 16 + c];
        yre = fmaf(x, twc[m], yre);
        yim = fmaf(x, tws[m], yim);
    }
    Yre[r * 16 + v] = yre;
    Yim[r * 16 + v] = yim;
    __syncthreads();

    // stage B: FFT along first axis: F[u][v] = sum_r Y[r][v] * tw[(r*u)&15]
    const int u = r;
    float fre = 0.f, fim = 0.f;
#pragma unroll
    for (int rr = 0; rr < 16; ++rr) {
        int m = (rr * u) & 15;
        float ar = Yre[rr * 16 + v], ai = Yim[rr * 16 + v];
        float wr = twc[m], wi = tws[m];
        fre += ar * wr - ai * wi;
        fim += ar * wi + ai * wr;
    }
    Fre[node * HID + tid] = fre;
    Fim[node * HID + tid] = fim;
}

// Kernel 2: per destination node: gather K=16 neighbor spectra, elementwise
// complex product, IFFT2 (conjugate DFT stages, *1/256), real part -> h[256],
// then out = h @ W_mlp + b_mlp.
__global__ __launch_bounds__(256) void k_gather_mlp(
    const int* __restrict__ nbr, const float* __restrict__ Fre,
    const float* __restrict__ Fim, const float* __restrict__ W_mlp,
    const float* __restrict__ b_mlp, float* __restrict__ out)
{
    const int node = blockIdx.x;
    const int tid  = threadIdx.x;  // 0..255, one spectrum element each
    __shared__ int   sn[KNBR];
    __shared__ float Pre[HID], Pim[HID];
    __shared__ float Zre[HID], Zim[HID];
    __shared__ float h[HID];
    __shared__ float twc[16], tws[16];       // exp(+2*pi*i*m/16)

    if (tid < KNBR) sn[tid] = nbr[node * KNBR + tid];
    if (tid < 16) {
        float a = (float)M_PI * (float)tid / 8.0f;
        twc[tid] = cosf(a);
        tws[tid] = sinf(a);
    }
    __syncthreads();

    // complex product across the 16 gathered spectra
    float pr = 1.0f, pi = 0.0f;
#pragma unroll
    for (int k = 0; k < KNBR; ++k) {
        int base = sn[k] * HID;
        float ar = Fre[base + tid];
        float ai = Fim[base + tid];
        float nr = pr * ar - pi * ai;
        pi       = pr * ai + pi * ar;
        pr       = nr;
    }
    Pre[tid] = pr;
    Pim[tid] = pi;
    __syncthreads();

    const int r = tid >> 4;
    const int v = tid & 15;

    // inverse stage along first axis: Z[r][v] = sum_u P[u][v] * tw+[(u*r)&15]
    float zr = 0.f, zi = 0.f;
#pragma unroll
    for (int u2 = 0; u2 < 16; ++u2) {
        int m = (u2 * r) & 15;
        float ar = Pre[u2 * 16 + v], ai = Pim[u2 * 16 + v];
        float wr = twc[m], wi = tws[m];
        zr += ar * wr - ai * wi;
        zi += ar * wi + ai * wr;
    }
    Zre[r * 16 + v] = zr;
    Zim[r * 16 + v] = zi;
    __syncthreads();

    // inverse stage along last axis, keep real part only, scale 1/256
    const int c = v;
    float hr = 0.f;
#pragma unroll
    for (int v2 = 0; v2 < 16; ++v2) {
        int m = (v2 * c) & 15;
        hr += Zre[r * 16 + v2] * twc[m] - Zim[r * 16 + v2] * tws[m];
    }
    h[r * 16 + c] = hr * (1.0f / 256.0f);
    __syncthreads();

    // MLP: out[j] = b_mlp[j] + sum_i h[i] * W_mlp[i*128+j]
    if (tid < OUT_DIM) {
        float acc = b_mlp[tid];
#pragma unroll 8
        for (int i = 0; i < HID; ++i)
            acc = fmaf(h[i], W_mlp[i * OUT_DIM + tid], acc);
        out[node * OUT_DIM + tid] = acc;
    }
}

extern "C" void kernel_launch(void* const* d_in, const int* in_sizes, int n_in,
                              void* d_out, int out_size, void* d_ws, size_t ws_size,
                              hipStream_t stream) {
    const float* feature   = (const float*)d_in[0];
    const int*   neighbors = (const int*)d_in[1];
    const float* W_aff     = (const float*)d_in[2];
    const float* b_aff     = (const float*)d_in[3];
    const float* W_mlp     = (const float*)d_in[4];
    const float* b_mlp     = (const float*)d_in[5];
    float*       out       = (float*)d_out;

    const int N = in_sizes[0] / IN_DIM;  // 20000

    float* Fre = (float*)d_ws;
    float* Fim = Fre + (size_t)N * HID;  // 2 * N * 256 * 4B = 41 MB in d_ws

    k_pre_fft<<<N, 256, 0, stream>>>(feature, W_aff, b_aff, Fre, Fim);
    k_gather_mlp<<<N, 256, 0, stream>>>(neighbors, Fre, Fim, W_mlp, b_mlp, out);
}

// Round 2
// 163.553 us; speedup vs baseline: 1.4450x; 1.4450x over previous
//
#include <hip/hip_runtime.h>
#include <math.h>

// N=20000, K=16, in_dim=128, out_dim=128, H1=H2=16, hidden=256
#define IN_DIM 128
#define HID 256
#define OUT_DIM 128
#define KNBR 16

// ---------------------------------------------------------------------------
// Prep A: W_fft2[d][e] = sum_rc W_aff[d][rc] * exp(-2*pi*i*(u*r+v*c)/16),
//         e=(u<<4)|v. Block 128 handles b_aff -> b_fft2.
// ---------------------------------------------------------------------------
__global__ __launch_bounds__(256) void k_prep_wfft(
    const float* __restrict__ W_aff, const float* __restrict__ b_aff,
    float2* __restrict__ W_fft2, float2* __restrict__ b_fft2)
{
    __shared__ float twc[16], tws[16];
    const int e = threadIdx.x, u = e >> 4, v = e & 15;
    if (e < 16) {
        float a = (float)M_PI * (float)e / 8.0f;  // 2*pi*e/16
        twc[e] = cosf(a);
        tws[e] = sinf(a);
    }
    __syncthreads();

    float ar = 0.f, ai = 0.f;
    if (blockIdx.x == 128) {
        for (int rc = 0; rc < 256; ++rc) {
            int m = (u * (rc >> 4) + v * (rc & 15)) & 15;
            float x = b_aff[rc];                      // uniform -> s_load
            ar = fmaf(x, twc[m], ar);
            ai = fmaf(x, -tws[m], ai);
        }
        b_fft2[e] = make_float2(ar, ai);
    } else {
        const int d = blockIdx.x;
        for (int rc = 0; rc < 256; ++rc) {
            int m = (u * (rc >> 4) + v * (rc & 15)) & 15;
            float x = W_aff[d * 256 + rc];            // uniform -> s_load
            ar = fmaf(x, twc[m], ar);
            ai = fmaf(x, -tws[m], ai);
        }
        W_fft2[d * 256 + e] = make_float2(ar, ai);
    }
}

// ---------------------------------------------------------------------------
// Prep B: W_eff2[e][j] = ( (1/256) sum_rc cos(th)*W_mlp[rc][j],
//                         -(1/256) sum_rc sin(th)*W_mlp[rc][j] ),
//         th = 2*pi*((u*r+v*c)&15)/16  (IFFT sign), folded with Re().
// ---------------------------------------------------------------------------
__global__ __launch_bounds__(128) void k_prep_weff(
    const float* __restrict__ W_mlp, float2* __restrict__ W_eff2)
{
    __shared__ float twc[16], tws[16];
    const int j = threadIdx.x;
    const int e = blockIdx.x, u = e >> 4, v = e & 15;
    if (j < 16) {
        float a = (float)M_PI * (float)j / 8.0f;
        twc[j] = cosf(a);
        tws[j] = sinf(a);
    }
    __syncthreads();

    float A = 0.f, B = 0.f;
    for (int rc = 0; rc < 256; ++rc) {
        int m = (u * (rc >> 4) + v * (rc & 15)) & 15;   // uniform per iter
        float wv = W_mlp[rc * 128 + j];                  // coalesced
        A = fmaf(wv, twc[m], A);
        B = fmaf(wv, -tws[m], B);
    }
    W_eff2[e * 128 + j] = make_float2(A * (1.0f / 256.0f), B * (1.0f / 256.0f));
}

// ---------------------------------------------------------------------------
// Kernel 1: spectra GEMM. 16 nodes/block, 256 threads (thread = element e).
// feature rows read as wave-uniform scalar loads; W_fft2 coalesced float2.
// ---------------------------------------------------------------------------
__global__ __launch_bounds__(256) void k_spectra(
    const float* __restrict__ feat, const float2* __restrict__ W_fft2,
    const float2* __restrict__ b_fft2, float2* __restrict__ F2)
{
    const int node0 = blockIdx.x * 16;
    const int e = threadIdx.x;

    float2 acc[16];
#pragma unroll
    for (int m = 0; m < 16; ++m) acc[m] = make_float2(0.f, 0.f);

#pragma unroll 4
    for (int d = 0; d < IN_DIM; ++d) {
        float2 w = W_fft2[d * 256 + e];               // coalesced 8B
#pragma unroll
        for (int m = 0; m < 16; ++m) {
            float fv = feat[(node0 + m) * IN_DIM + d]; // uniform -> s_load
            acc[m].x = fmaf(fv, w.x, acc[m].x);
            acc[m].y = fmaf(fv, w.y, acc[m].y);
        }
    }

    float2 b = b_fft2[e];
#pragma unroll
    for (int m = 0; m < 16; ++m) {
        F2[(node0 + m) * 256 + e] = make_float2(acc[m].x + b.x, acc[m].y + b.y);
    }
}

// ---------------------------------------------------------------------------
// Kernel 2: gather + complex product (registers) + folded MLP.
// 8 nodes/block, 256 threads. Product phase: thread = element e (P kept in
// regs). MLP phase: wave w consumes its own e-slice [w*64, w*64+64) via
// v_readlane broadcast; each lane accumulates j=lane and j=lane+64 for all
// 8 nodes; cross-wave reduction through LDS.
// ---------------------------------------------------------------------------
__global__ __launch_bounds__(256) void k_gather_mlp(
    const int* __restrict__ nbr, const float2* __restrict__ F2,
    const float2* __restrict__ W_eff2, const float* __restrict__ b_mlp,
    float* __restrict__ out)
{
    const int node0 = blockIdx.x * 8;
    const int tid = threadIdx.x;
    const int lane = tid & 63;
    const int wv = tid >> 6;

    __shared__ float part[4][8][128];   // 16 KB

    // ---- product phase: P[m] for element e=tid, all 8 nodes, in registers
    float pr[8], pi[8];
#pragma unroll
    for (int m = 0; m < 8; ++m) {
        float2 f[KNBR];
#pragma unroll
        for (int k = 0; k < KNBR; ++k) {
            int nb = nbr[(node0 + m) * KNBR + k];      // uniform -> s_load
            f[k] = F2[nb * 256 + tid];                 // coalesced 8B gather
        }
        // tree product of 16 complex values (shorter dep chain)
        float2 g[8];
#pragma unroll
        for (int k = 0; k < 8; ++k) {
            g[k].x = f[2 * k].x * f[2 * k + 1].x - f[2 * k].y * f[2 * k + 1].y;
            g[k].y = f[2 * k].x * f[2 * k + 1].y + f[2 * k].y * f[2 * k + 1].x;
        }
#pragma unroll
        for (int k = 0; k < 4; ++k) {
            float2 a = g[2 * k], b = g[2 * k + 1];
            g[k].x = a.x * b.x - a.y * b.y;
            g[k].y = a.x * b.y + a.y * b.x;
        }
        {
            float2 a = g[0], b = g[1];
            g[0].x = a.x * b.x - a.y * b.y;
            g[0].y = a.x * b.y + a.y * b.x;
            a = g[2]; b = g[3];
            g[1].x = a.x * b.x - a.y * b.y;
            g[1].y = a.x * b.y + a.y * b.x;
            a = g[0]; b = g[1];
            pr[m] = a.x * b.x - a.y * b.y;
            pi[m] = a.x * b.y + a.y * b.x;
        }
    }

    // ---- MLP phase: wave wv handles e in [wv*64, wv*64+64)
    float acc0[8], acc1[8];
#pragma unroll
    for (int m = 0; m < 8; ++m) { acc0[m] = 0.f; acc1[m] = 0.f; }

#pragma unroll 4
    for (int le = 0; le < 64; ++le) {                  // le is wave-uniform
        int e = wv * 64 + le;
        float2 w0 = W_eff2[e * 128 + lane];
        float2 w1 = W_eff2[e * 128 + lane + 64];
#pragma unroll
        for (int m = 0; m < 8; ++m) {
            float sre = __int_as_float(
                __builtin_amdgcn_readlane(__float_as_int(pr[m]), le));
            float sim = __int_as_float(
                __builtin_amdgcn_readlane(__float_as_int(pi[m]), le));
            acc0[m] = fmaf(sre, w0.x, fmaf(sim, w0.y, acc0[m]));
            acc1[m] = fmaf(sre, w1.x, fmaf(sim, w1.y, acc1[m]));
        }
    }

#pragma unroll
    for (int m = 0; m < 8; ++m) {
        part[wv][m][lane]      = acc0[m];
        part[wv][m][lane + 64] = acc1[m];
    }
    __syncthreads();

    // ---- final reduction over 4 waves: 1024 outputs, 4 per thread
    {
        const int m = tid >> 5;           // (tid*4) >> 7
        const int j = (tid & 31) * 4;
        float4 s = *(const float4*)&b_mlp[j];
#pragma unroll
        for (int w = 0; w < 4; ++w) {
            const float4 p = *(const float4*)&part[w][m][j];
            s.x += p.x; s.y += p.y; s.z += p.z; s.w += p.w;
        }
        *(float4*)&out[(node0 + m) * OUT_DIM + j] = s;
    }
}

extern "C" void kernel_launch(void* const* d_in, const int* in_sizes, int n_in,
                              void* d_out, int out_size, void* d_ws, size_t ws_size,
                              hipStream_t stream) {
    const float* feature   = (const float*)d_in[0];
    const int*   neighbors = (const int*)d_in[1];
    const float* W_aff     = (const float*)d_in[2];
    const float* b_aff     = (const float*)d_in[3];
    const float* W_mlp     = (const float*)d_in[4];
    const float* b_mlp     = (const float*)d_in[5];
    float*       out       = (float*)d_out;

    const int N = in_sizes[0] / IN_DIM;   // 20000

    // workspace layout (all float2, 8B-aligned)
    float2* W_fft2 = (float2*)d_ws;            // 128*256
    float2* b_fft2 = W_fft2 + 128 * 256;       // 256
    float2* W_eff2 = b_fft2 + 256;             // 256*128
    float2* F2     = W_eff2 + 256 * 128;       // N*256  (~41 MB)

    k_prep_wfft<<<129, 256, 0, stream>>>(W_aff, b_aff, W_fft2, b_fft2);
    k_prep_weff<<<256, 128, 0, stream>>>(W_mlp, W_eff2);
    k_spectra<<<N / 16, 256, 0, stream>>>(feature, W_fft2, b_fft2, F2);
    k_gather_mlp<<<N / 8, 256, 0, stream>>>(neighbors, F2, W_eff2, b_mlp, out);
}

// Round 3
// 118.930 us; speedup vs baseline: 1.9871x; 1.3752x over previous
//
#include <hip/hip_runtime.h>
#include <math.h>

// N=20000, K=16, in_dim=128, out_dim=128, H1=H2=16
// Hermitian-reduced spectrum: e = v*16 + u, v=0..8, u=0..15  -> NE=144
#define IN_DIM 128
#define NE 144
#define OUT_DIM 128
#define KNBR 16

__device__ __forceinline__ float2 cmul(float2 a, float2 b) {
    return make_float2(a.x * b.x - a.y * b.y, a.x * b.y + a.y * b.x);
}

__device__ __forceinline__ float2 cprod16(const float2* f) {
    float2 g[8];
#pragma unroll
    for (int k = 0; k < 8; ++k) g[k] = cmul(f[2 * k], f[2 * k + 1]);
#pragma unroll
    for (int k = 0; k < 4; ++k) g[k] = cmul(g[2 * k], g[2 * k + 1]);
    float2 a = cmul(g[0], g[1]);
    float2 b = cmul(g[2], g[3]);
    return cmul(a, b);
}

// ---------------------------------------------------------------------------
// Prep A: W_fft2[d][e] = sum_rc W_aff[d][rc] * exp(-2*pi*i*(u*r+v*c)/16),
//         e = v*16+u, v<=8. Block 128 does b_aff -> b_fft2.
// ---------------------------------------------------------------------------
__global__ __launch_bounds__(256) void k_prep_wfft(
    const float* __restrict__ W_aff, const float* __restrict__ b_aff,
    float2* __restrict__ W_fft2, float2* __restrict__ b_fft2)
{
    __shared__ float twc[16], tws[16];
    const int e = threadIdx.x;
    if (e < 16) {
        float a = (float)M_PI * (float)e / 8.0f;   // 2*pi*e/16
        twc[e] = cosf(a);
        tws[e] = sinf(a);
    }
    __syncthreads();
    if (e >= NE) return;
    const int u = e & 15, v = e >> 4;
    const float* src = (blockIdx.x == 128) ? b_aff : (W_aff + blockIdx.x * 256);
    float ar = 0.f, ai = 0.f;
    for (int rc = 0; rc < 256; ++rc) {
        int m = (u * (rc >> 4) + v * (rc & 15)) & 15;
        float x = src[rc];                          // uniform -> s_load
        ar = fmaf(x, twc[m], ar);
        ai = fmaf(x, -tws[m], ai);
    }
    if (blockIdx.x == 128) b_fft2[e] = make_float2(ar, ai);
    else                   W_fft2[blockIdx.x * NE + e] = make_float2(ar, ai);
}

// ---------------------------------------------------------------------------
// Prep B: folded (IFFT2 + Re + Hermitian weight) x W_mlp:
//   Wt[e][j] = (1/256) sum_rc exp(+2*pi*i*(u*r+v*c)/16) * W_mlp[rc][j]
//   stored (A,B) = ( wt*Re(Wt), -wt*Im(Wt) ),  wt = (v==0||v==8) ? 1 : 2
//   so out += ReP*A + ImP*B  ==  wt * Re(P * Wt)
// ---------------------------------------------------------------------------
__global__ __launch_bounds__(128) void k_prep_weff(
    const float* __restrict__ W_mlp, float2* __restrict__ W_eff2)
{
    __shared__ float twc[16], tws[16];
    const int j = threadIdx.x;
    const int e = blockIdx.x;            // 0..143
    const int u = e & 15, v = e >> 4;
    if (j < 16) {
        float a = (float)M_PI * (float)j / 8.0f;
        twc[j] = cosf(a);
        tws[j] = sinf(a);
    }
    __syncthreads();
    float A = 0.f, B = 0.f;
    for (int rc = 0; rc < 256; ++rc) {
        int m = (u * (rc >> 4) + v * (rc & 15)) & 15;
        float wv_ = W_mlp[rc * 128 + j];            // coalesced
        A = fmaf(wv_, twc[m], A);
        B = fmaf(wv_, tws[m], B);
    }
    const float s = ((v == 0) || (v == 8)) ? (1.0f / 256.0f) : (2.0f / 256.0f);
    W_eff2[e * 128 + j] = make_float2(A * s, -B * s);
}

// ---------------------------------------------------------------------------
// Kernel 1: spectra GEMM (Hermitian half only). 16 nodes/block, 192 threads,
// threads 0..143 own element e; feature reads are wave-uniform (s_load).
// ---------------------------------------------------------------------------
__global__ __launch_bounds__(192) void k_spectra(
    const float* __restrict__ feat, const float2* __restrict__ W_fft2,
    const float2* __restrict__ b_fft2, float2* __restrict__ F2)
{
    const int t = threadIdx.x;
    if (t >= NE) return;
    const int node0 = blockIdx.x * 16;

    float2 acc[16];
#pragma unroll
    for (int m = 0; m < 16; ++m) acc[m] = make_float2(0.f, 0.f);

#pragma unroll 4
    for (int d = 0; d < IN_DIM; ++d) {
        float2 w = W_fft2[d * NE + t];              // coalesced 8B
#pragma unroll
        for (int m = 0; m < 16; ++m) {
            float fv = feat[(node0 + m) * IN_DIM + d];  // uniform -> s_load
            acc[m].x = fmaf(fv, w.x, acc[m].x);
            acc[m].y = fmaf(fv, w.y, acc[m].y);
        }
    }

    float2 b = b_fft2[t];
#pragma unroll
    for (int m = 0; m < 16; ++m)
        F2[(node0 + m) * NE + t] = make_float2(acc[m].x + b.x, acc[m].y + b.y);
}

// ---------------------------------------------------------------------------
// Kernel 2: gather + complex product + folded MLP. 8 nodes/block, 256 thr.
// Product: wave w owns nodes {2w, 2w+1}; lane covers e = lane, lane+64,
// lane+128(<16). Neighbor rows are wave-uniform -> s_load. P goes to LDS.
// MLP: wave w owns e-slice [36w, 36w+36); P broadcast via uniform ds_read.
// ---------------------------------------------------------------------------
__global__ __launch_bounds__(256) void k_gather_mlp(
    const int* __restrict__ nbr, const float2* __restrict__ F2,
    const float2* __restrict__ W_eff2, const float* __restrict__ b_mlp,
    float* __restrict__ out)
{
    const int node0 = blockIdx.x * 8;
    const int tid  = threadIdx.x;
    const int lane = tid & 63;
    const int w    = __builtin_amdgcn_readfirstlane(tid >> 6);

    __shared__ float2 P_lds[8][NE];       // 9.2 KB
    __shared__ float  part[4][8][128];    // 16 KB

    // ---- product phase
#pragma unroll
    for (int mi = 0; mi < 2; ++mi) {
        const int m = 2 * w + mi;
        const int* nrow = nbr + (node0 + m) * KNBR;

        float2 fA[KNBR], fB[KNBR];
        const int eA = lane, eB = lane + 64;
#pragma unroll
        for (int k = 0; k < KNBR; ++k) {
            const int nb = nrow[k];                   // uniform -> s_load
            const float2* base = F2 + nb * NE;
            fA[k] = base[eA];                         // coalesced 8B gather
            fB[k] = base[eB];
        }
        P_lds[m][eA] = cprod16(fA);
        P_lds[m][eB] = cprod16(fB);

        if (lane < 16) {
            const int eC = lane + 128;
            float2 fC[KNBR];
#pragma unroll
            for (int k = 0; k < KNBR; ++k)
                fC[k] = F2[nrow[k] * NE + eC];
            P_lds[m][eC] = cprod16(fC);
        }
    }
    __syncthreads();

    // ---- MLP phase: wave w handles e in [36w, 36w+36)
    float acc0[8], acc1[8];
#pragma unroll
    for (int m = 0; m < 8; ++m) { acc0[m] = 0.f; acc1[m] = 0.f; }

    const int e0 = w * 36;
#pragma unroll 4
    for (int le = 0; le < 36; ++le) {
        const int e = e0 + le;                        // wave-uniform
        const float2 w0 = W_eff2[e * 128 + lane];
        const float2 w1 = W_eff2[e * 128 + 64 + lane];
#pragma unroll
        for (int m = 0; m < 8; ++m) {
            const float2 p = P_lds[m][e];             // uniform -> broadcast
            acc0[m] = fmaf(p.x, w0.x, fmaf(p.y, w0.y, acc0[m]));
            acc1[m] = fmaf(p.x, w1.x, fmaf(p.y, w1.y, acc1[m]));
        }
    }

#pragma unroll
    for (int m = 0; m < 8; ++m) {
        part[w][m][lane]      = acc0[m];
        part[w][m][lane + 64] = acc1[m];
    }
    __syncthreads();

    // ---- cross-wave reduction: 1024 outputs, 4 per thread
    {
        const int m = tid >> 5;
        const int j = (tid & 31) * 4;
        float4 s = *(const float4*)&b_mlp[j];
#pragma unroll
        for (int w4 = 0; w4 < 4; ++w4) {
            const float4 p = *(const float4*)&part[w4][m][j];
            s.x += p.x; s.y += p.y; s.z += p.z; s.w += p.w;
        }
        *(float4*)&out[(node0 + m) * OUT_DIM + j] = s;
    }
}

extern "C" void kernel_launch(void* const* d_in, const int* in_sizes, int n_in,
                              void* d_out, int out_size, void* d_ws, size_t ws_size,
                              hipStream_t stream) {
    const float* feature   = (const float*)d_in[0];
    const int*   neighbors = (const int*)d_in[1];
    const float* W_aff     = (const float*)d_in[2];
    const float* b_aff     = (const float*)d_in[3];
    const float* W_mlp     = (const float*)d_in[4];
    const float* b_mlp     = (const float*)d_in[5];
    float*       out       = (float*)d_out;

    const int N = in_sizes[0] / IN_DIM;   // 20000

    float2* W_fft2 = (float2*)d_ws;            // 128*144
    float2* b_fft2 = W_fft2 + 128 * NE;        // 144
    float2* W_eff2 = b_fft2 + NE;              // 144*128
    float2* F2     = W_eff2 + NE * 128;        // N*144  (~23 MB)

    k_prep_wfft<<<129, 256, 0, stream>>>(W_aff, b_aff, W_fft2, b_fft2);
    k_prep_weff<<<NE, 128, 0, stream>>>(W_mlp, W_eff2);
    k_spectra<<<N / 16, 192, 0, stream>>>(feature, W_fft2, b_fft2, F2);
    k_gather_mlp<<<N / 8, 256, 0, stream>>>(neighbors, F2, W_eff2, b_mlp, out);
}